// Round 2
// baseline (2679.966 us; speedup 1.0000x reference)
//
#include <hip/hip_runtime.h>

// ---------------------------------------------------------------------------
// PIDMultiHeadAttention — Round 2.
// Changes vs round 1 (which produced NaN):
//  * ws footprint 80.3 MiB -> 33 MiB; control arrays (flag/csum/gates) at the
//    BASE of d_ws (suspected OOB-at-tail garbage caused the NaN).
//  * Runtime input-dtype detection (bf16 vs fp32 wire); all input loads branch
//    on a device flag. Output store branches likewise.
//  * Intermediates (integral-mean, Q, K, V, attn-out) stored bf16 in ws.
// ---------------------------------------------------------------------------

#define D_MODEL 1024
#define T_SEQ   2048
#define B_SZ    2
#define M_ROWS  (B_SZ * T_SEQ)   // 4096
#define N_HEADS 16
#define D_HEAD  64

typedef unsigned short u16;
typedef unsigned int   u32;

__device__ __forceinline__ float bf2f(u16 u) {
    union { u32 i; float f; } c; c.i = ((u32)u) << 16; return c.f;
}
__device__ __forceinline__ u16 f2bf(float f) {
    union { float f; u32 i; } c; c.f = f;
    u32 i = c.i;
    i += 0x7FFFu + ((i >> 16) & 1u);   // RNE
    return (u16)(i >> 16);
}

// flag: 0 = bf16 wire, 1 = fp32 wire
__device__ __forceinline__ float ldin(const void* p, int i, int fl) {
    return fl ? ((const float*)p)[i] : bf2f(((const u16*)p)[i]);
}
__device__ __forceinline__ void ldin4(const void* p, int i, int fl, float o[4]) {
    if (fl) {
        float4 t = *(const float4*)((const float*)p + i);
        o[0] = t.x; o[1] = t.y; o[2] = t.z; o[3] = t.w;
    } else {
        ushort4 u = *(const ushort4*)((const u16*)p + i);
        o[0] = bf2f(u.x); o[1] = bf2f(u.y); o[2] = bf2f(u.z); o[3] = bf2f(u.w);
    }
}
__device__ __forceinline__ void ldb4(const u16* p, int i, float o[4]) {
    ushort4 u = *(const ushort4*)(p + i);
    o[0] = bf2f(u.x); o[1] = bf2f(u.y); o[2] = bf2f(u.z); o[3] = bf2f(u.w);
}

// ---------------------------------------------------------------------------
// 0) wire-dtype detection: fp32 N(0,1) words parse as sane floats (~100%),
//    bf16-pair words do so only ~16% of the time.
// ---------------------------------------------------------------------------
__global__ void detect_kernel(const u32* __restrict__ x, int* __restrict__ flag)
{
    if (threadIdx.x == 0 && blockIdx.x == 0) {
        int good = 0;
        for (int i = 0; i < 256; ++i) {
            union { u32 u; float f; } c; c.u = x[i];
            float a = fabsf(c.f);
            if (c.f == c.f && a > 1e-8f && a < 1e4f) ++good;
        }
        *flag = (good >= 192) ? 1 : 0;
    }
}

// ---------------------------------------------------------------------------
// 1a) per-chunk column sums: 16 chunks of 128 timesteps per (b, d) column
// ---------------------------------------------------------------------------
__global__ __launch_bounds__(256) void scan_partial(
    const void* __restrict__ x, float* __restrict__ csum,
    const int* __restrict__ flagp)
{
    int fl = *flagp;
    int tid = blockIdx.x * 256 + threadIdx.x;   // 32768 = B * 16 * D
    int b = tid >> 14;
    int c = (tid >> 10) & 15;
    int d = tid & 1023;
    int base = (b * T_SEQ + c * 128) * D_MODEL + d;
    float s = 0.f;
#pragma unroll 8
    for (int t = 0; t < 128; ++t) s += ldin(x, base + t * D_MODEL, fl);
    csum[tid] = s;
}

// ---------------------------------------------------------------------------
// 1b) prefix over chunk sums + local cumsum -> running mean, stored bf16
// ---------------------------------------------------------------------------
__global__ __launch_bounds__(256) void scan_final(
    const void* __restrict__ x, const float* __restrict__ csum,
    u16* __restrict__ integ, const int* __restrict__ flagp)
{
    int fl = *flagp;
    int tid = blockIdx.x * 256 + threadIdx.x;
    int b = tid >> 14;
    int c = (tid >> 10) & 15;
    int d = tid & 1023;
    float pre = 0.f;
    int cbase = (b << 14) | d;
    for (int cc = 0; cc < c; ++cc) pre += csum[cbase + (cc << 10)];
    int base = (b * T_SEQ + c * 128) * D_MODEL + d;
    float run = pre;
    int t0 = c * 128;
    for (int t = 0; t < 128; ++t) {
        run += ldin(x, base + t * D_MODEL, fl);
        integ[base + t * D_MODEL] = f2bf(run / (float)(t0 + t + 1));
    }
}

// ---------------------------------------------------------------------------
// 2) gate softmax: one wave per row, 9 dots of length 1024 + softmax3 each
// ---------------------------------------------------------------------------
__global__ __launch_bounds__(64) void gates_kernel(
    const void* __restrict__ x,
    const void* __restrict__ qWg, const void* __restrict__ qbg,
    const void* __restrict__ kWg, const void* __restrict__ kbg,
    const void* __restrict__ vWg, const void* __restrict__ vbg,
    float* __restrict__ gq, float* __restrict__ gk, float* __restrict__ gv,
    const int* __restrict__ flagp)
{
    int fl = *flagp;
    int row = blockIdx.x;
    int l = threadIdx.x;
    int xb = row * D_MODEL;
    float p[9];
#pragma unroll
    for (int j = 0; j < 9; ++j) p[j] = 0.f;
#pragma unroll 4
    for (int i = 0; i < 16; ++i) {
        int d = l + 64 * i;
        float xv = ldin(x, xb + d, fl);
        p[0] += xv * ldin(qWg, d, fl);
        p[1] += xv * ldin(qWg, 1024 + d, fl);
        p[2] += xv * ldin(qWg, 2048 + d, fl);
        p[3] += xv * ldin(kWg, d, fl);
        p[4] += xv * ldin(kWg, 1024 + d, fl);
        p[5] += xv * ldin(kWg, 2048 + d, fl);
        p[6] += xv * ldin(vWg, d, fl);
        p[7] += xv * ldin(vWg, 1024 + d, fl);
        p[8] += xv * ldin(vWg, 2048 + d, fl);
    }
#pragma unroll
    for (int off = 32; off > 0; off >>= 1) {
#pragma unroll
        for (int j = 0; j < 9; ++j) p[j] += __shfl_down(p[j], off);
    }
    if (l == 0) {
        const void* bgs[3] = { qbg, kbg, vbg };
        float* outs[3] = { gq, gk, gv };
#pragma unroll
        for (int pr = 0; pr < 3; ++pr) {
            float a0 = p[pr * 3 + 0] + ldin(bgs[pr], 0, fl);
            float a1 = p[pr * 3 + 1] + ldin(bgs[pr], 1, fl);
            float a2 = p[pr * 3 + 2] + ldin(bgs[pr], 2, fl);
            float mx = fmaxf(a0, fmaxf(a1, a2));
            float e0 = __expf(a0 - mx), e1 = __expf(a1 - mx), e2 = __expf(a2 - mx);
            float inv = 1.f / (e0 + e1 + e2);
            outs[pr][row * 3 + 0] = e0 * inv;
            outs[pr][row * 3 + 1] = e1 * inv;
            outs[pr][row * 3 + 2] = e2 * inv;
        }
    }
}

// ---------------------------------------------------------------------------
// 3) PID projection GEMM: C[m,n] = sum_seg g_seg[m] * (A_seg @ W_seg^T)
//    seg0: A = x, seg1: A = running-mean (bf16 ws), seg2: A = dx on the fly.
//    fp32 tiled: BM=BN=64, BK=16, 256 thr, 4x4 microtile. Output bf16.
// ---------------------------------------------------------------------------
#define BM 64
#define BN 64
#define BK 16
#define LDP 68

__global__ __launch_bounds__(256) void pid_gemm(
    const void* __restrict__ X,
    const u16* __restrict__ I,
    const void* __restrict__ Wp,
    const void* __restrict__ Wi,
    const void* __restrict__ Wd,
    const float* __restrict__ G,
    u16* __restrict__ C,
    const int* __restrict__ flagp)
{
    int fl = *flagp;
    __shared__ __align__(16) float As[BK][LDP];
    __shared__ __align__(16) float Bs[BK][LDP];
    int tid = threadIdx.x;
    int m0 = blockIdx.y * BM;
    int n0 = blockIdx.x * BN;
    int lm = tid >> 2;          // 0..63 : row this thread stages
    int lk = (tid & 3) * 4;     // 0,4,8,12
    int gm = m0 + lm;
    int gn = n0 + lm;
    int tm = (tid >> 4) * 4;
    int tn = (tid & 15) * 4;
    float gsc[3] = { G[gm * 3 + 0], G[gm * 3 + 1], G[gm * 3 + 2] };
    bool t0row = ((gm & (T_SEQ - 1)) == 0);

    float acc[4][4];
#pragma unroll
    for (int i = 0; i < 4; ++i)
#pragma unroll
        for (int j = 0; j < 4; ++j) acc[i][j] = 0.f;

    for (int seg = 0; seg < 3; ++seg) {
        const void* W = (seg == 0) ? Wp : (seg == 1 ? Wi : Wd);
        float sc = gsc[seg];
        for (int k0 = 0; k0 < D_MODEL; k0 += BK) {
            float av[4];
            if (seg == 1) {
                ldb4(I, gm * D_MODEL + k0 + lk, av);
            } else {
                ldin4(X, gm * D_MODEL + k0 + lk, fl, av);
                if (seg == 2) {
                    if (t0row) {
                        av[0] = av[1] = av[2] = av[3] = 0.f;
                    } else {
                        float pv[4];
                        ldin4(X, (gm - 1) * D_MODEL + k0 + lk, fl, pv);
                        av[0] -= pv[0]; av[1] -= pv[1];
                        av[2] -= pv[2]; av[3] -= pv[3];
                    }
                }
            }
#pragma unroll
            for (int j = 0; j < 4; ++j) As[lk + j][lm] = av[j] * sc;
            float wv[4];
            ldin4(W, gn * D_MODEL + k0 + lk, fl, wv);
#pragma unroll
            for (int j = 0; j < 4; ++j) Bs[lk + j][lm] = wv[j];
            __syncthreads();
#pragma unroll
            for (int kk = 0; kk < BK; ++kk) {
                float4 a4 = *(const float4*)&As[kk][tm];
                float4 b4 = *(const float4*)&Bs[kk][tn];
                float a[4] = { a4.x, a4.y, a4.z, a4.w };
                float b[4] = { b4.x, b4.y, b4.z, b4.w };
#pragma unroll
                for (int i2 = 0; i2 < 4; ++i2)
#pragma unroll
                    for (int j2 = 0; j2 < 4; ++j2)
                        acc[i2][j2] += a[i2] * b[j2];
            }
            __syncthreads();
        }
    }
#pragma unroll
    for (int i2 = 0; i2 < 4; ++i2) {
        ushort4 o;
        o.x = f2bf(acc[i2][0]); o.y = f2bf(acc[i2][1]);
        o.z = f2bf(acc[i2][2]); o.w = f2bf(acc[i2][3]);
        *(ushort4*)&C[(m0 + tm + i2) * D_MODEL + n0 + tn] = o;
    }
}

// ---------------------------------------------------------------------------
// 4) causal attention, flash-style online softmax. 1 wave per (b,h,64 q-rows);
//    lane = q-row. K/V tiles in LDS (broadcast reads). fp32 math, bf16 I/O.
// ---------------------------------------------------------------------------
__global__ __launch_bounds__(64) void attn_kernel(
    const u16* __restrict__ Q, const u16* __restrict__ K,
    const u16* __restrict__ V, u16* __restrict__ O)
{
    int bx = blockIdx.x;          // B*H*(T/64) = 1024
    int qt = bx & 31;             // q-tile
    int bh = bx >> 5;
    int b = bh >> 4, h = bh & 15;
    int l = threadIdx.x;

    __shared__ __align__(16) float Ks[64][LDP];
    __shared__ __align__(16) float Vs[64][LDP];

    int q0 = qt * 64;
    int rowbase = (b * T_SEQ) * D_MODEL + h * D_HEAD;

    for (int j = 0; j < 64; ++j)
        Ks[j][l] = bf2f(Q[rowbase + (q0 + j) * D_MODEL + l]);
    __syncthreads();
    float q[64];
#pragma unroll
    for (int d = 0; d < 64; ++d) q[d] = Ks[l][d];
    __syncthreads();

    float acc[64];
#pragma unroll
    for (int d = 0; d < 64; ++d) acc[d] = 0.f;
    float mrun = -1e30f, lsum = 0.f;
    const float rs = 0.125f;      // 1/sqrt(64)

    for (int kt = 0; kt <= qt; ++kt) {
        for (int j = 0; j < 64; ++j) {
            Ks[j][l] = bf2f(K[rowbase + (kt * 64 + j) * D_MODEL + l]);
            Vs[j][l] = bf2f(V[rowbase + (kt * 64 + j) * D_MODEL + l]);
        }
        __syncthreads();
        int kmax = (kt == qt) ? (l + 1) : 64;   // causal
        for (int k = 0; k < kmax; ++k) {
            float s = 0.f;
#pragma unroll
            for (int d = 0; d < 64; ++d) s += q[d] * Ks[k][d];
            s *= rs;
            if (s > mrun) {
                float alpha = __expf(mrun - s);
                lsum *= alpha;
#pragma unroll
                for (int d = 0; d < 64; ++d) acc[d] *= alpha;
                mrun = s;
            }
            float p = __expf(s - mrun);
            lsum += p;
#pragma unroll
            for (int d = 0; d < 64; ++d) acc[d] += p * Vs[k][d];
        }
        __syncthreads();
    }
    float inv = 1.f / lsum;
#pragma unroll
    for (int d = 0; d < 64; ++d)
        O[rowbase + (q0 + l) * D_MODEL + d] = f2bf(acc[d] * inv);
}

// ---------------------------------------------------------------------------
// 5) output projection: out = AO @ oW^T + ob
// ---------------------------------------------------------------------------
__global__ __launch_bounds__(256) void out_gemm(
    const u16* __restrict__ A,
    const void* __restrict__ W,
    const void* __restrict__ bias,
    void* __restrict__ outp,
    const int* __restrict__ flagp)
{
    int fl = *flagp;
    __shared__ __align__(16) float As[BK][LDP];
    __shared__ __align__(16) float Bs[BK][LDP];
    int tid = threadIdx.x;
    int m0 = blockIdx.y * BM;
    int n0 = blockIdx.x * BN;
    int lm = tid >> 2;
    int lk = (tid & 3) * 4;
    int gm = m0 + lm;
    int gn = n0 + lm;
    int tm = (tid >> 4) * 4;
    int tn = (tid & 15) * 4;

    float acc[4][4];
#pragma unroll
    for (int i = 0; i < 4; ++i)
#pragma unroll
        for (int j = 0; j < 4; ++j) acc[i][j] = 0.f;

    for (int k0 = 0; k0 < D_MODEL; k0 += BK) {
        float av[4];
        ldb4(A, gm * D_MODEL + k0 + lk, av);
#pragma unroll
        for (int j = 0; j < 4; ++j) As[lk + j][lm] = av[j];
        float wv[4];
        ldin4(W, gn * D_MODEL + k0 + lk, fl, wv);
#pragma unroll
        for (int j = 0; j < 4; ++j) Bs[lk + j][lm] = wv[j];
        __syncthreads();
#pragma unroll
        for (int kk = 0; kk < BK; ++kk) {
            float4 a4 = *(const float4*)&As[kk][tm];
            float4 b4 = *(const float4*)&Bs[kk][tn];
            float a[4] = { a4.x, a4.y, a4.z, a4.w };
            float b[4] = { b4.x, b4.y, b4.z, b4.w };
#pragma unroll
            for (int i2 = 0; i2 < 4; ++i2)
#pragma unroll
                for (int j2 = 0; j2 < 4; ++j2)
                    acc[i2][j2] += a[i2] * b[j2];
        }
        __syncthreads();
    }
#pragma unroll
    for (int i2 = 0; i2 < 4; ++i2) {
        float r[4];
#pragma unroll
        for (int j2 = 0; j2 < 4; ++j2)
            r[j2] = acc[i2][j2] + ldin(bias, n0 + tn + j2, fl);
        int oidx = (m0 + tm + i2) * D_MODEL + n0 + tn;
        if (fl) {
            float4 o; o.x = r[0]; o.y = r[1]; o.z = r[2]; o.w = r[3];
            *(float4*)&((float*)outp)[oidx] = o;
        } else {
            ushort4 o;
            o.x = f2bf(r[0]); o.y = f2bf(r[1]); o.z = f2bf(r[2]); o.w = f2bf(r[3]);
            *(ushort4*)&((u16*)outp)[oidx] = o;
        }
    }
}

// ---------------------------------------------------------------------------
extern "C" void kernel_launch(void* const* d_in, const int* in_sizes, int n_in,
                              void* d_out, int out_size, void* d_ws, size_t ws_size,
                              hipStream_t stream)
{
    const void* x   = d_in[0];
    const void* qWp = d_in[1];
    const void* qWi = d_in[2];
    const void* qWd = d_in[3];
    const void* qWg = d_in[4];
    const void* qbg = d_in[5];
    const void* kWp = d_in[6];
    const void* kWi = d_in[7];
    const void* kWd = d_in[8];
    const void* kWg = d_in[9];
    const void* kbg = d_in[10];
    const void* vWp = d_in[11];
    const void* vWi = d_in[12];
    const void* vWd = d_in[13];
    const void* vWg = d_in[14];
    const void* vbg = d_in[15];
    const void* oW  = d_in[16];
    const void* ob  = d_in[17];

    // ws layout (33 MiB total; control arrays at BASE):
    //   [0]        int flag
    //   [64f]      csum   32768 f
    //   [+32832f]  gq/gk/gv 3*12288 f
    //   @1 MiB     integ  4M bf16 (8 MiB)   -- aliased by AO after projections
    //   @9 MiB     Qb     4M bf16
    //   @17 MiB    Kb     4M bf16
    //   @25 MiB    Vb     4M bf16           -- ends at 33 MiB
    int*   flag = (int*)d_ws;
    float* fws  = (float*)d_ws;
    float* csum = fws + 64;
    float* gq   = csum + 32768;
    float* gk   = gq + 3 * M_ROWS;
    float* gv   = gk + 3 * M_ROWS;
    const size_t SZ = (size_t)M_ROWS * D_MODEL;   // 4M elements
    u16* integ = (u16*)((char*)d_ws + (1u << 20));
    u16* AO    = integ;                            // alias, disjoint in time
    u16* Qb    = integ + SZ;
    u16* Kb    = Qb + SZ;
    u16* Vb    = Kb + SZ;

    detect_kernel<<<1, 64, 0, stream>>>((const u32*)x, flag);
    scan_partial<<<128, 256, 0, stream>>>(x, csum, flag);
    scan_final<<<128, 256, 0, stream>>>(x, csum, integ, flag);
    gates_kernel<<<M_ROWS, 64, 0, stream>>>(x, qWg, qbg, kWg, kbg, vWg, vbg,
                                            gq, gk, gv, flag);
    dim3 gg(D_MODEL / BN, M_ROWS / BM);   // (16, 64)
    pid_gemm<<<gg, 256, 0, stream>>>(x, integ, qWp, qWi, qWd, gq, Qb, flag);
    pid_gemm<<<gg, 256, 0, stream>>>(x, integ, kWp, kWi, kWd, gk, Kb, flag);
    pid_gemm<<<gg, 256, 0, stream>>>(x, integ, vWp, vWi, vWd, gv, Vb, flag);
    attn_kernel<<<B_SZ * N_HEADS * (T_SEQ / 64), 64, 0, stream>>>(Qb, Kb, Vb, AO);
    out_gemm<<<gg, 256, 0, stream>>>(AO, oW, ob, d_out, flag);
}

// Round 3
// 1035.512 us; speedup vs baseline: 2.5881x; 2.5881x over previous
//
#include <hip/hip_runtime.h>

// ---------------------------------------------------------------------------
// PIDMultiHeadAttention — Round 3: MFMA everywhere.
//  * mfma_f32_16x16x32_bf16 GEMMs (128x128x32 tiles, padded-LDS VALU staging)
//  * PID A' (g-scaled X / running-mean / diff) fused into GEMM A-staging
//  * MFMA flash attention (wave = 16 q rows, K/V LDS tiles, P via LDS)
//  * ws layout identical footprint to round 2 (proven to fit): 33 MiB
// ---------------------------------------------------------------------------

#define D_MODEL 1024
#define T_SEQ   2048
#define B_SZ    2
#define M_ROWS  (B_SZ * T_SEQ)   // 4096
#define N_HEADS 16
#define D_HEAD  64

typedef unsigned short u16;
typedef unsigned int   u32;

typedef short  short8  __attribute__((ext_vector_type(8)));
typedef float  float4v __attribute__((ext_vector_type(4)));

__device__ __forceinline__ float bf2f(u16 u) {
    union { u32 i; float f; } c; c.i = ((u32)u) << 16; return c.f;
}
__device__ __forceinline__ u16 f2bf(float f) {
    union { float f; u32 i; } c; c.f = f;
    u32 i = c.i;
    i += 0x7FFFu + ((i >> 16) & 1u);   // RNE
    return (u16)(i >> 16);
}
__device__ __forceinline__ float ldin(const void* p, int i, int fl) {
    return fl ? ((const float*)p)[i] : bf2f(((const u16*)p)[i]);
}
// load 8 consecutive wire elements -> f32
__device__ __forceinline__ void ld8w(const void* p, int idx, int fl, float v[8]) {
    if (fl) {
        float4 a = *(const float4*)((const float*)p + idx);
        float4 b = *(const float4*)((const float*)p + idx + 4);
        v[0]=a.x; v[1]=a.y; v[2]=a.z; v[3]=a.w;
        v[4]=b.x; v[5]=b.y; v[6]=b.z; v[7]=b.w;
    } else {
        ushort4 a = *(const ushort4*)((const u16*)p + idx);
        ushort4 b = *(const ushort4*)((const u16*)p + idx + 4);
        v[0]=bf2f(a.x); v[1]=bf2f(a.y); v[2]=bf2f(a.z); v[3]=bf2f(a.w);
        v[4]=bf2f(b.x); v[5]=bf2f(b.y); v[6]=bf2f(b.z); v[7]=bf2f(b.w);
    }
}

// ---------------------------------------------------------------------------
// 0) wire-dtype detection (same as round 2 — passed)
// ---------------------------------------------------------------------------
__global__ void detect_kernel(const u32* __restrict__ x, int* __restrict__ flag)
{
    if (threadIdx.x == 0 && blockIdx.x == 0) {
        int good = 0;
        for (int i = 0; i < 256; ++i) {
            union { u32 u; float f; } c; c.u = x[i];
            float a = fabsf(c.f);
            if (c.f == c.f && a > 1e-8f && a < 1e4f) ++good;
        }
        *flag = (good >= 192) ? 1 : 0;
    }
}

// ---------------------------------------------------------------------------
// 1) cumulative-mean scan (two-kernel chunked), output bf16
// ---------------------------------------------------------------------------
__global__ __launch_bounds__(256) void scan_partial(
    const void* __restrict__ x, float* __restrict__ csum,
    const int* __restrict__ flagp)
{
    int fl = *flagp;
    int tid = blockIdx.x * 256 + threadIdx.x;   // 32768 = B * 16 * D
    int b = tid >> 14;
    int c = (tid >> 10) & 15;
    int d = tid & 1023;
    int base = (b * T_SEQ + c * 128) * D_MODEL + d;
    float s = 0.f;
#pragma unroll 8
    for (int t = 0; t < 128; ++t) s += ldin(x, base + t * D_MODEL, fl);
    csum[tid] = s;
}

__global__ __launch_bounds__(256) void scan_final(
    const void* __restrict__ x, const float* __restrict__ csum,
    u16* __restrict__ integ, const int* __restrict__ flagp)
{
    int fl = *flagp;
    int tid = blockIdx.x * 256 + threadIdx.x;
    int b = tid >> 14;
    int c = (tid >> 10) & 15;
    int d = tid & 1023;
    float pre = 0.f;
    int cbase = (b << 14) | d;
    for (int cc = 0; cc < c; ++cc) pre += csum[cbase + (cc << 10)];
    int base = (b * T_SEQ + c * 128) * D_MODEL + d;
    float run = pre;
    int t0 = c * 128;
    for (int t = 0; t < 128; ++t) {
        run += ldin(x, base + t * D_MODEL, fl);
        integ[base + t * D_MODEL] = f2bf(run / (float)(t0 + t + 1));
    }
}

// ---------------------------------------------------------------------------
// 2) gate softmax (unchanged from round 2 — passed)
// ---------------------------------------------------------------------------
__global__ __launch_bounds__(64) void gates_kernel(
    const void* __restrict__ x,
    const void* __restrict__ qWg, const void* __restrict__ qbg,
    const void* __restrict__ kWg, const void* __restrict__ kbg,
    const void* __restrict__ vWg, const void* __restrict__ vbg,
    float* __restrict__ gq, float* __restrict__ gk, float* __restrict__ gv,
    const int* __restrict__ flagp)
{
    int fl = *flagp;
    int row = blockIdx.x;
    int l = threadIdx.x;
    int xb = row * D_MODEL;
    float p[9];
#pragma unroll
    for (int j = 0; j < 9; ++j) p[j] = 0.f;
#pragma unroll 4
    for (int i = 0; i < 16; ++i) {
        int d = l + 64 * i;
        float xv = ldin(x, xb + d, fl);
        p[0] += xv * ldin(qWg, d, fl);
        p[1] += xv * ldin(qWg, 1024 + d, fl);
        p[2] += xv * ldin(qWg, 2048 + d, fl);
        p[3] += xv * ldin(kWg, d, fl);
        p[4] += xv * ldin(kWg, 1024 + d, fl);
        p[5] += xv * ldin(kWg, 2048 + d, fl);
        p[6] += xv * ldin(vWg, d, fl);
        p[7] += xv * ldin(vWg, 1024 + d, fl);
        p[8] += xv * ldin(vWg, 2048 + d, fl);
    }
#pragma unroll
    for (int off = 32; off > 0; off >>= 1) {
#pragma unroll
        for (int j = 0; j < 9; ++j) p[j] += __shfl_down(p[j], off);
    }
    if (l == 0) {
        const void* bgs[3] = { qbg, kbg, vbg };
        float* outs[3] = { gq, gk, gv };
#pragma unroll
        for (int pr = 0; pr < 3; ++pr) {
            float a0 = p[pr * 3 + 0] + ldin(bgs[pr], 0, fl);
            float a1 = p[pr * 3 + 1] + ldin(bgs[pr], 1, fl);
            float a2 = p[pr * 3 + 2] + ldin(bgs[pr], 2, fl);
            float mx = fmaxf(a0, fmaxf(a1, a2));
            float e0 = __expf(a0 - mx), e1 = __expf(a1 - mx), e2 = __expf(a2 - mx);
            float inv = 1.f / (e0 + e1 + e2);
            outs[pr][row * 3 + 0] = e0 * inv;
            outs[pr][row * 3 + 1] = e1 * inv;
            outs[pr][row * 3 + 2] = e2 * inv;
        }
    }
}

// ---------------------------------------------------------------------------
// 3) MFMA GEMM, 128x128x32 tiles, 4 waves of 64x64.
//    MODE 0: PID projection. A' built on the fly:
//      seg0 = g0*x, seg1 = g1*runmean(bf16 ws), seg2 = g2*(x[t]-x[t-1]);
//      K = 3072 (seg-major). Epilogue -> head-major bf16 [b,h,t,d].
//    MODE 1: plain bf16 A (attention out), K = 1024, epilogue adds bias,
//      writes wire dtype.
//    LDS rows padded to 40 elems (80 B): b128 frag reads are 2-way max (free).
// ---------------------------------------------------------------------------
#define LDA 40

template<int MODE>
__global__ __launch_bounds__(256) void mfma_gemm(
    const void* __restrict__ X, const u16* __restrict__ Ib,
    const u16* __restrict__ Abf,
    const void* __restrict__ W0, const void* __restrict__ W1,
    const void* __restrict__ W2,
    const float* __restrict__ G,
    const void* __restrict__ bias,
    u16* __restrict__ Chead, void* __restrict__ outp,
    const int* __restrict__ flagp, int Ktot)
{
    int fl = *flagp;
    __shared__ __align__(16) u16 As[128 * LDA];
    __shared__ __align__(16) u16 Bs[128 * LDA];

    int tid = threadIdx.x;
    int l   = tid & 63;
    int w   = tid >> 6;
    int wm  = w >> 1, wn = w & 1;
    int m0  = blockIdx.y * 128;
    int n0  = blockIdx.x * 128;

    int srow = tid >> 2;          // 0..63 staging row within 64-row chunk
    int skof = (tid & 3) * 8;     // 0,8,16,24

    float gcoef[2][3];
    if (MODE == 0) {
#pragma unroll
        for (int c = 0; c < 2; ++c) {
            int gm = m0 + c * 64 + srow;
#pragma unroll
            for (int s = 0; s < 3; ++s) gcoef[c][s] = G[gm * 3 + s];
        }
    }

    float4v acc[4][4];
#pragma unroll
    for (int i = 0; i < 4; ++i)
#pragma unroll
        for (int j = 0; j < 4; ++j)
#pragma unroll
            for (int r = 0; r < 4; ++r) acc[i][j][r] = 0.f;

    int lane15 = l & 15;
    int quad   = l >> 4;

    for (int k0 = 0; k0 < Ktot; k0 += 32) {
        int seg  = k0 >> 10;          // 0..2 for MODE 0; 0 for MODE 1
        int ksrc = k0 & 1023;

        // ---- stage A tile (128 x 32) ----
#pragma unroll
        for (int c = 0; c < 2; ++c) {
            int row = c * 64 + srow;
            int gm  = m0 + row;
            short8 pk;
            if (MODE == 0) {
                float v[8];
                if (seg == 0) {
                    ld8w(X, gm * 1024 + ksrc + skof, fl, v);
                } else if (seg == 1) {
                    ushort4 a = *(const ushort4*)&Ib[gm * 1024 + ksrc + skof];
                    ushort4 b = *(const ushort4*)&Ib[gm * 1024 + ksrc + skof + 4];
                    v[0]=bf2f(a.x); v[1]=bf2f(a.y); v[2]=bf2f(a.z); v[3]=bf2f(a.w);
                    v[4]=bf2f(b.x); v[5]=bf2f(b.y); v[6]=bf2f(b.z); v[7]=bf2f(b.w);
                } else {
                    if ((gm & (T_SEQ - 1)) == 0) {
#pragma unroll
                        for (int j = 0; j < 8; ++j) v[j] = 0.f;
                    } else {
                        float pv[8];
                        ld8w(X, gm * 1024 + ksrc + skof, fl, v);
                        ld8w(X, (gm - 1) * 1024 + ksrc + skof, fl, pv);
#pragma unroll
                        for (int j = 0; j < 8; ++j) v[j] -= pv[j];
                    }
                }
                float sc = gcoef[c][seg];
#pragma unroll
                for (int j = 0; j < 8; ++j) pk[j] = (short)f2bf(v[j] * sc);
            } else {
                ushort4 a = *(const ushort4*)&Abf[gm * 1024 + ksrc + skof];
                ushort4 b = *(const ushort4*)&Abf[gm * 1024 + ksrc + skof + 4];
                pk[0]=a.x; pk[1]=a.y; pk[2]=a.z; pk[3]=a.w;
                pk[4]=b.x; pk[5]=b.y; pk[6]=b.z; pk[7]=b.w;
            }
            *(short8*)&As[row * LDA + skof] = pk;
        }

        // ---- stage B tile (128 x 32) from W_seg (wire dtype) ----
        const void* W = (MODE == 0) ? ((seg == 0) ? W0 : (seg == 1 ? W1 : W2)) : W0;
#pragma unroll
        for (int c = 0; c < 2; ++c) {
            int row = c * 64 + srow;
            int gn  = n0 + row;
            short8 pk;
            if (fl) {
                float v[8];
                ld8w(W, gn * 1024 + ksrc + skof, 1, v);
#pragma unroll
                for (int j = 0; j < 8; ++j) pk[j] = (short)f2bf(v[j]);
            } else {
                ushort4 a = *(const ushort4*)((const u16*)W + gn * 1024 + ksrc + skof);
                ushort4 b = *(const ushort4*)((const u16*)W + gn * 1024 + ksrc + skof + 4);
                pk[0]=a.x; pk[1]=a.y; pk[2]=a.z; pk[3]=a.w;
                pk[4]=b.x; pk[5]=b.y; pk[6]=b.z; pk[7]=b.w;
            }
            *(short8*)&Bs[row * LDA + skof] = pk;
        }

        __syncthreads();

        // ---- 16 MFMAs: wave tile 64x64, one K=32 step ----
        short8 af[4], bf[4];
#pragma unroll
        for (int ms = 0; ms < 4; ++ms)
            af[ms] = *(const short8*)&As[(wm * 64 + ms * 16 + lane15) * LDA + quad * 8];
#pragma unroll
        for (int ns = 0; ns < 4; ++ns)
            bf[ns] = *(const short8*)&Bs[(wn * 64 + ns * 16 + lane15) * LDA + quad * 8];
#pragma unroll
        for (int ms = 0; ms < 4; ++ms)
#pragma unroll
            for (int ns = 0; ns < 4; ++ns)
                acc[ms][ns] = __builtin_amdgcn_mfma_f32_16x16x32_bf16(
                    af[ms], bf[ns], acc[ms][ns], 0, 0, 0);

        __syncthreads();
    }

    // ---- epilogue ----
#pragma unroll
    for (int ms = 0; ms < 4; ++ms) {
#pragma unroll
        for (int r = 0; r < 4; ++r) {
            int m = m0 + wm * 64 + ms * 16 + quad * 4 + r;
#pragma unroll
            for (int ns = 0; ns < 4; ++ns) {
                int n = n0 + wn * 64 + ns * 16 + lane15;
                float vv = acc[ms][ns][r];
                if (MODE == 0) {
                    int b = m >> 11, t = m & (T_SEQ - 1);
                    int h = n >> 6,  d = n & 63;
                    Chead[(((b << 4) + h) * T_SEQ + t) * 64 + d] = f2bf(vv);
                } else {
                    vv += ldin(bias, n, fl);
                    if (fl) ((float*)outp)[m * 1024 + n] = vv;
                    else    ((u16*)outp)[m * 1024 + n] = f2bf(vv);
                }
            }
        }
    }
}

// ---------------------------------------------------------------------------
// 4) MFMA flash attention. Block = 256 thr (4 waves) = 64 q-rows; wave = 16.
//    Inputs Q/K/V head-major bf16 [b*16+h][t][64]. Output AO row-major
//    [b*T+t][1024] bf16.
// ---------------------------------------------------------------------------
__global__ __launch_bounds__(256) void attn_mfma(
    const u16* __restrict__ Qh, const u16* __restrict__ Kh,
    const u16* __restrict__ Vh, u16* __restrict__ AO)
{
    int bx = blockIdx.x;          // 1024 = B*H*(T/64)
    int qt = bx & 31;
    int bh = bx >> 5;             // 0..31
    int h  = bh & 15;
    int b  = bh >> 4;
    int tid = threadIdx.x;
    int l   = tid & 63;
    int w   = tid >> 6;
    int lane15 = l & 15;
    int quad   = l >> 4;

    __shared__ __align__(16) u16 Ks[64 * 72];
    __shared__ __align__(16) u16 Vt[64 * 72];   // transposed: [d][t_local]
    __shared__ __align__(16) u16 Ps[4 * 16 * 72];

    const u16* Qb = Qh + bh * (T_SEQ * 64);
    const u16* Kb = Kh + bh * (T_SEQ * 64);
    const u16* Vb = Vh + bh * (T_SEQ * 64);

    // Q fragments: wave w covers q rows qt*64 + w*16 .. +16
    int qrow = qt * 64 + w * 16 + lane15;
    short8 qf[2];
#pragma unroll
    for (int ks = 0; ks < 2; ++ks)
        qf[ks] = *(const short8*)&Qb[qrow * 64 + ks * 32 + quad * 8];

    float4v oacc[4];
#pragma unroll
    for (int ds = 0; ds < 4; ++ds)
#pragma unroll
        for (int r = 0; r < 4; ++r) oacc[ds][r] = 0.f;
    float mrun[4], lrun[4];
#pragma unroll
    for (int r = 0; r < 4; ++r) { mrun[r] = -1e30f; lrun[r] = 0.f; }

    int srow = tid >> 2;          // staging: row 0..63
    int sdc  = (tid & 3) * 16;    // d col 0,16,32,48

    for (int kt = 0; kt <= qt; ++kt) {
        // ---- stage K (row-major, pad 72) and V (transposed, pad 72) ----
        {
            const u16* kp = &Kb[(kt * 64 + srow) * 64 + sdc];
            ushort4 a = *(const ushort4*)kp;
            ushort4 c = *(const ushort4*)(kp + 4);
            ushort4 d2 = *(const ushort4*)(kp + 8);
            ushort4 e = *(const ushort4*)(kp + 12);
            short8 p0, p1;
            p0[0]=a.x; p0[1]=a.y; p0[2]=a.z; p0[3]=a.w;
            p0[4]=c.x; p0[5]=c.y; p0[6]=c.z; p0[7]=c.w;
            p1[0]=d2.x; p1[1]=d2.y; p1[2]=d2.z; p1[3]=d2.w;
            p1[4]=e.x; p1[5]=e.y; p1[6]=e.z; p1[7]=e.w;
            *(short8*)&Ks[srow * 72 + sdc] = p0;
            *(short8*)&Ks[srow * 72 + sdc + 8] = p1;

            const u16* vp = &Vb[(kt * 64 + srow) * 64 + sdc];
            u16 vv[16];
            *(ushort4*)&vv[0]  = *(const ushort4*)vp;
            *(ushort4*)&vv[4]  = *(const ushort4*)(vp + 4);
            *(ushort4*)&vv[8]  = *(const ushort4*)(vp + 8);
            *(ushort4*)&vv[12] = *(const ushort4*)(vp + 12);
#pragma unroll
            for (int e2 = 0; e2 < 16; ++e2)
                Vt[(sdc + e2) * 72 + srow] = vv[e2];
        }
        __syncthreads();

        // ---- S = Q K^T (16x64 per wave) ----
        float4v sacc[4];
#pragma unroll
        for (int ns = 0; ns < 4; ++ns)
#pragma unroll
            for (int r = 0; r < 4; ++r) sacc[ns][r] = 0.f;
#pragma unroll
        for (int ks = 0; ks < 2; ++ks) {
#pragma unroll
            for (int ns = 0; ns < 4; ++ns) {
                short8 bfk = *(const short8*)&Ks[(ns * 16 + lane15) * 72 + ks * 32 + quad * 8];
                sacc[ns] = __builtin_amdgcn_mfma_f32_16x16x32_bf16(
                    qf[ks], bfk, sacc[ns], 0, 0, 0);
            }
        }

        // ---- scale + causal mask + online softmax ----
        int qg0 = qt * 64 + w * 16 + quad * 4;   // + r
#pragma unroll
        for (int ns = 0; ns < 4; ++ns) {
            int kg = kt * 64 + ns * 16 + lane15;
#pragma unroll
            for (int r = 0; r < 4; ++r) {
                float s = sacc[ns][r] * 0.125f;
                sacc[ns][r] = (kg > qg0 + r) ? -1e30f : s;
            }
        }
#pragma unroll
        for (int r = 0; r < 4; ++r) {
            float mx = fmaxf(fmaxf(sacc[0][r], sacc[1][r]),
                             fmaxf(sacc[2][r], sacc[3][r]));
#pragma unroll
            for (int m2 = 1; m2 < 16; m2 <<= 1)
                mx = fmaxf(mx, __shfl_xor(mx, m2, 64));
            float mnew = fmaxf(mrun[r], mx);
            float al = __expf(mrun[r] - mnew);
            float rs = 0.f;
#pragma unroll
            for (int ns = 0; ns < 4; ++ns) {
                float p = __expf(sacc[ns][r] - mnew);
                sacc[ns][r] = p;
                rs += p;
            }
#pragma unroll
            for (int m2 = 1; m2 < 16; m2 <<= 1)
                rs += __shfl_xor(rs, m2, 64);
            lrun[r] = lrun[r] * al + rs;
            mrun[r] = mnew;
#pragma unroll
            for (int ds = 0; ds < 4; ++ds) oacc[ds][r] *= al;
        }

        // ---- P -> LDS (C-layout scatter), then PV MFMAs ----
        u16* Pw = &Ps[w * 16 * 72];
#pragma unroll
        for (int ns = 0; ns < 4; ++ns)
#pragma unroll
            for (int r = 0; r < 4; ++r)
                Pw[(quad * 4 + r) * 72 + ns * 16 + lane15] = f2bf(sacc[ns][r]);

#pragma unroll
        for (int ks = 0; ks < 2; ++ks) {
            short8 afp = *(const short8*)&Pw[lane15 * 72 + ks * 32 + quad * 8];
#pragma unroll
            for (int ds = 0; ds < 4; ++ds) {
                short8 bfv = *(const short8*)&Vt[(ds * 16 + lane15) * 72 + ks * 32 + quad * 8];
                oacc[ds] = __builtin_amdgcn_mfma_f32_16x16x32_bf16(
                    afp, bfv, oacc[ds], 0, 0, 0);
            }
        }
        __syncthreads();
    }

    // ---- epilogue: divide by l, store row-major [b*T+t][h*64+d] ----
#pragma unroll
    for (int r = 0; r < 4; ++r) {
        float inv = 1.f / lrun[r];
        int t = qt * 64 + w * 16 + quad * 4 + r;
        int orow = (b * T_SEQ + t) * 1024 + h * 64;
#pragma unroll
        for (int ds = 0; ds < 4; ++ds)
            AO[orow + ds * 16 + lane15] = f2bf(oacc[ds][r] * inv);
    }
}

// ---------------------------------------------------------------------------
extern "C" void kernel_launch(void* const* d_in, const int* in_sizes, int n_in,
                              void* d_out, int out_size, void* d_ws, size_t ws_size,
                              hipStream_t stream)
{
    const void* x   = d_in[0];
    const void* qWp = d_in[1];
    const void* qWi = d_in[2];
    const void* qWd = d_in[3];
    const void* qWg = d_in[4];
    const void* qbg = d_in[5];
    const void* kWp = d_in[6];
    const void* kWi = d_in[7];
    const void* kWd = d_in[8];
    const void* kWg = d_in[9];
    const void* kbg = d_in[10];
    const void* vWp = d_in[11];
    const void* vWi = d_in[12];
    const void* vWd = d_in[13];
    const void* vWg = d_in[14];
    const void* vbg = d_in[15];
    const void* oW  = d_in[16];
    const void* ob  = d_in[17];

    // ws layout (33 MiB total — identical footprint to the round-2 pass):
    //   [0]       int flag
    //   [64f]     csum 32768 f
    //   [+]       gq/gk/gv 3*12288 f
    //   @1  MiB   Ib   4M bf16 (running mean)  -- aliased by AO after pid GEMMs
    //   @9  MiB   Qh   4M bf16 (head-major)
    //   @17 MiB   Kh   4M bf16
    //   @25 MiB   Vh   4M bf16
    int*   flag = (int*)d_ws;
    float* fws  = (float*)d_ws;
    float* csum = fws + 64;
    float* gq   = csum + 32768;
    float* gk   = gq + 3 * M_ROWS;
    float* gv   = gk + 3 * M_ROWS;
    const size_t SZ = (size_t)M_ROWS * D_MODEL;
    u16* Ib = (u16*)((char*)d_ws + (1u << 20));
    u16* AO = Ib;                  // alias, disjoint in time
    u16* Qh = Ib + SZ;
    u16* Kh = Qh + SZ;
    u16* Vh = Kh + SZ;

    detect_kernel<<<1, 64, 0, stream>>>((const u32*)x, flag);
    scan_partial<<<128, 256, 0, stream>>>(x, csum, flag);
    scan_final<<<128, 256, 0, stream>>>(x, csum, Ib, flag);
    gates_kernel<<<M_ROWS, 64, 0, stream>>>(x, qWg, qbg, kWg, kbg, vWg, vbg,
                                            gq, gk, gv, flag);

    dim3 gg(D_MODEL / 128, M_ROWS / 128);   // (8, 32)
    mfma_gemm<0><<<gg, 256, 0, stream>>>(x, Ib, nullptr, qWp, qWi, qWd,
                                         gq, nullptr, Qh, nullptr, flag, 3072);
    mfma_gemm<0><<<gg, 256, 0, stream>>>(x, Ib, nullptr, kWp, kWi, kWd,
                                         gk, nullptr, Kh, nullptr, flag, 3072);
    mfma_gemm<0><<<gg, 256, 0, stream>>>(x, Ib, nullptr, vWp, vWi, vWd,
                                         gv, nullptr, Vh, nullptr, flag, 3072);

    attn_mfma<<<B_SZ * N_HEADS * (T_SEQ / 64), 256, 0, stream>>>(Qh, Kh, Vh, AO);

    mfma_gemm<1><<<gg, 256, 0, stream>>>(nullptr, nullptr, AO, oW, nullptr, nullptr,
                                         nullptr, ob, nullptr, d_out, flag, 1024);
}

// Round 4
// 656.477 us; speedup vs baseline: 4.0823x; 1.5774x over previous
//
#include <hip/hip_runtime.h>

// ---------------------------------------------------------------------------
// PIDMultiHeadAttention — Round 4.
// vs round 3 (1035 us, gemm = 3x251 us at 1 block/CU latency-bound):
//  * q/k/v projections merged into ONE dispatch (grid z=3 -> 768 blocks,
//    3 blocks/CU instead of 1)
//  * K-loop software-pipelined: double-buffered LDS + register prefetch,
//    one barrier per iteration
//  * fragment-major linear LDS layout (no padding) — every b128 LDS op is a
//    contiguous 1KiB/wave access (round 3: 6.3M bank-conflict cycles)
//  * fp32-wire path pre-rounds to bf16 at load (register pressure)
// ---------------------------------------------------------------------------

#define D_MODEL 1024
#define T_SEQ   2048
#define B_SZ    2
#define M_ROWS  (B_SZ * T_SEQ)   // 4096
#define N_HEADS 16
#define D_HEAD  64

typedef unsigned short u16;
typedef unsigned int   u32;

typedef short  short8  __attribute__((ext_vector_type(8)));
typedef float  float4v __attribute__((ext_vector_type(4)));

__device__ __forceinline__ float bf2f(u16 u) {
    union { u32 i; float f; } c; c.i = ((u32)u) << 16; return c.f;
}
__device__ __forceinline__ u16 f2bf(float f) {
    union { float f; u32 i; } c; c.f = f;
    u32 i = c.i;
    i += 0x7FFFu + ((i >> 16) & 1u);   // RNE
    return (u16)(i >> 16);
}
__device__ __forceinline__ float ldin(const void* p, int i, int fl) {
    return fl ? ((const float*)p)[i] : bf2f(((const u16*)p)[i]);
}

// ---------------------------------------------------------------------------
// 0) wire-dtype detection (unchanged — passing since round 2)
// ---------------------------------------------------------------------------
__global__ void detect_kernel(const u32* __restrict__ x, int* __restrict__ flag)
{
    if (threadIdx.x == 0 && blockIdx.x == 0) {
        int good = 0;
        for (int i = 0; i < 256; ++i) {
            union { u32 u; float f; } c; c.u = x[i];
            float a = fabsf(c.f);
            if (c.f == c.f && a > 1e-8f && a < 1e4f) ++good;
        }
        *flag = (good >= 192) ? 1 : 0;
    }
}

// ---------------------------------------------------------------------------
// 1) cumulative-mean scan (unchanged)
// ---------------------------------------------------------------------------
__global__ __launch_bounds__(256) void scan_partial(
    const void* __restrict__ x, float* __restrict__ csum,
    const int* __restrict__ flagp)
{
    int fl = *flagp;
    int tid = blockIdx.x * 256 + threadIdx.x;   // 32768 = B * 16 * D
    int b = tid >> 14;
    int c = (tid >> 10) & 15;
    int d = tid & 1023;
    int base = (b * T_SEQ + c * 128) * D_MODEL + d;
    float s = 0.f;
#pragma unroll 8
    for (int t = 0; t < 128; ++t) s += ldin(x, base + t * D_MODEL, fl);
    csum[tid] = s;
}

__global__ __launch_bounds__(256) void scan_final(
    const void* __restrict__ x, const float* __restrict__ csum,
    u16* __restrict__ integ, const int* __restrict__ flagp)
{
    int fl = *flagp;
    int tid = blockIdx.x * 256 + threadIdx.x;
    int b = tid >> 14;
    int c = (tid >> 10) & 15;
    int d = tid & 1023;
    float pre = 0.f;
    int cbase = (b << 14) | d;
    for (int cc = 0; cc < c; ++cc) pre += csum[cbase + (cc << 10)];
    int base = (b * T_SEQ + c * 128) * D_MODEL + d;
    float run = pre;
    int t0 = c * 128;
    for (int t = 0; t < 128; ++t) {
        run += ldin(x, base + t * D_MODEL, fl);
        integ[base + t * D_MODEL] = f2bf(run / (float)(t0 + t + 1));
    }
}

// ---------------------------------------------------------------------------
// 2) gate softmax (unchanged)
// ---------------------------------------------------------------------------
__global__ __launch_bounds__(64) void gates_kernel(
    const void* __restrict__ x,
    const void* __restrict__ qWg, const void* __restrict__ qbg,
    const void* __restrict__ kWg, const void* __restrict__ kbg,
    const void* __restrict__ vWg, const void* __restrict__ vbg,
    float* __restrict__ gq, float* __restrict__ gk, float* __restrict__ gv,
    const int* __restrict__ flagp)
{
    int fl = *flagp;
    int row = blockIdx.x;
    int l = threadIdx.x;
    int xb = row * D_MODEL;
    float p[9];
#pragma unroll
    for (int j = 0; j < 9; ++j) p[j] = 0.f;
#pragma unroll 4
    for (int i = 0; i < 16; ++i) {
        int d = l + 64 * i;
        float xv = ldin(x, xb + d, fl);
        p[0] += xv * ldin(qWg, d, fl);
        p[1] += xv * ldin(qWg, 1024 + d, fl);
        p[2] += xv * ldin(qWg, 2048 + d, fl);
        p[3] += xv * ldin(kWg, d, fl);
        p[4] += xv * ldin(kWg, 1024 + d, fl);
        p[5] += xv * ldin(kWg, 2048 + d, fl);
        p[6] += xv * ldin(vWg, d, fl);
        p[7] += xv * ldin(vWg, 1024 + d, fl);
        p[8] += xv * ldin(vWg, 2048 + d, fl);
    }
#pragma unroll
    for (int off = 32; off > 0; off >>= 1) {
#pragma unroll
        for (int j = 0; j < 9; ++j) p[j] += __shfl_down(p[j], off);
    }
    if (l == 0) {
        const void* bgs[3] = { qbg, kbg, vbg };
        float* outs[3] = { gq, gk, gv };
#pragma unroll
        for (int pr = 0; pr < 3; ++pr) {
            float a0 = p[pr * 3 + 0] + ldin(bgs[pr], 0, fl);
            float a1 = p[pr * 3 + 1] + ldin(bgs[pr], 1, fl);
            float a2 = p[pr * 3 + 2] + ldin(bgs[pr], 2, fl);
            float mx = fmaxf(a0, fmaxf(a1, a2));
            float e0 = __expf(a0 - mx), e1 = __expf(a1 - mx), e2 = __expf(a2 - mx);
            float inv = 1.f / (e0 + e1 + e2);
            outs[pr][row * 3 + 0] = e0 * inv;
            outs[pr][row * 3 + 1] = e1 * inv;
            outs[pr][row * 3 + 2] = e2 * inv;
        }
    }
}

// ---------------------------------------------------------------------------
// 3) MFMA GEMM, 128x128x32 tiles, double-buffered, software-pipelined.
//    MODE 0: PID projection (K=3072 seg-major, blockIdx.z picks q/k/v).
//    MODE 1: attention-out projection (K=1024, +bias, wire-dtype store).
//    LDS: fragment-major linear layout:
//      off_u16(row, chunk) = ((row/16)*4 + chunk)*128 + (row%16)*8
//    so wave-level b128 stores/loads are 1KiB-contiguous (conflict-free).
// ---------------------------------------------------------------------------
#define LOFF(row, c) (((((row) >> 4) * 4 + (c)) << 7) + (((row) & 15) << 3))

struct GemmArgs {
    const void* W[3][3];
    const float* G[3];
    u16* C[3];
};

template<int MODE>
__global__ __launch_bounds__(256, 3) void mfma_gemm(
    const void* __restrict__ X, const u16* __restrict__ Ib,
    const u16* __restrict__ Abf, GemmArgs args,
    const void* __restrict__ bias, void* __restrict__ outp,
    const int* __restrict__ flagp, int Ktot)
{
    int fl = *flagp;
    __shared__ __align__(16) u16 As[2 * 4096];
    __shared__ __align__(16) u16 Bs[2 * 4096];

    int tid = threadIdx.x;
    int l = tid & 63, w = tid >> 6;
    int wm = w >> 1, wn = w & 1;
    int m0 = blockIdx.y * 128, n0 = blockIdx.x * 128;
    int z = blockIdx.z;
    int lane15 = l & 15, quad = l >> 4;
    int srow = tid >> 2;       // staging row 0..63 (chunk of 64)
    int cs = tid & 3;          // k-chunk 0..3 (8 elems each)
    int skof = cs * 8;

    const void* W0; const void* W1; const void* W2;
    const float* G = nullptr;
    u16* Chead = nullptr;
    if (MODE == 0) {
        W0 = args.W[z][0]; W1 = args.W[z][1]; W2 = args.W[z][2];
        G = args.G[z]; Chead = args.C[z];
    } else {
        W0 = args.W[0][0]; W1 = W0; W2 = W0;
    }

    float gcoef[2][3];
    if (MODE == 0) {
#pragma unroll
        for (int c = 0; c < 2; ++c)
#pragma unroll
            for (int s = 0; s < 3; ++s)
                gcoef[c][s] = G[(m0 + c * 64 + srow) * 3 + s];
    }

    // prefetch registers (bf16 payload)
    ushort4 ra[2][4];   // A: [c][cur0,cur1,prev0,prev1]
    ushort4 rb[2][2];   // B: [c][2]

    auto cvt4 = [](float4 t) {
        ushort4 u;
        u.x = f2bf(t.x); u.y = f2bf(t.y); u.z = f2bf(t.z); u.w = f2bf(t.w);
        return u;
    };
    auto ld8 = [&](const void* p, int idx, ushort4& o0, ushort4& o1) {
        if (fl) {
            o0 = cvt4(*(const float4*)((const float*)p + idx));
            o1 = cvt4(*(const float4*)((const float*)p + idx + 4));
        } else {
            o0 = *(const ushort4*)((const u16*)p + idx);
            o1 = *(const ushort4*)((const u16*)p + idx + 4);
        }
    };

    auto load_phase = [&](int k0) {
        int seg = k0 >> 10, ksrc = k0 & 1023;
        const void* Wse = (MODE == 0) ? (seg == 0 ? W0 : (seg == 1 ? W1 : W2)) : W0;
#pragma unroll
        for (int c = 0; c < 2; ++c) {
            int gm = m0 + c * 64 + srow;
            int idx = gm * 1024 + ksrc + skof;
            if (MODE == 1) {
                ra[c][0] = *(const ushort4*)&Abf[idx];
                ra[c][1] = *(const ushort4*)&Abf[idx + 4];
            } else if (seg == 1) {
                ra[c][0] = *(const ushort4*)&Ib[idx];
                ra[c][1] = *(const ushort4*)&Ib[idx + 4];
            } else {
                ld8(X, idx, ra[c][0], ra[c][1]);
                if (seg == 2 && (gm & (T_SEQ - 1)) != 0)
                    ld8(X, idx - 1024, ra[c][2], ra[c][3]);
            }
            int gn = n0 + c * 64 + srow;
            ld8(Wse, gn * 1024 + ksrc + skof, rb[c][0], rb[c][1]);
        }
    };

    auto unp8 = [](ushort4 a, ushort4 b, float v[8]) {
        v[0] = bf2f(a.x); v[1] = bf2f(a.y); v[2] = bf2f(a.z); v[3] = bf2f(a.w);
        v[4] = bf2f(b.x); v[5] = bf2f(b.y); v[6] = bf2f(b.z); v[7] = bf2f(b.w);
    };

    auto store_phase = [&](int k0, int buf) {
        int seg = k0 >> 10;
        u16* Ad = As + buf * 4096;
        u16* Bd = Bs + buf * 4096;
#pragma unroll
        for (int c = 0; c < 2; ++c) {
            int row = c * 64 + srow;
            short8 pk;
            if (MODE == 1) {
                pk[0] = (short)ra[c][0].x; pk[1] = (short)ra[c][0].y;
                pk[2] = (short)ra[c][0].z; pk[3] = (short)ra[c][0].w;
                pk[4] = (short)ra[c][1].x; pk[5] = (short)ra[c][1].y;
                pk[6] = (short)ra[c][1].z; pk[7] = (short)ra[c][1].w;
            } else {
                float v[8];
                unp8(ra[c][0], ra[c][1], v);
                if (seg == 2) {
                    int gm = m0 + row;
                    if ((gm & (T_SEQ - 1)) == 0) {
#pragma unroll
                        for (int j = 0; j < 8; ++j) v[j] = 0.f;
                    } else {
                        float pv[8];
                        unp8(ra[c][2], ra[c][3], pv);
#pragma unroll
                        for (int j = 0; j < 8; ++j) v[j] -= pv[j];
                    }
                }
                float sc = gcoef[c][seg];
#pragma unroll
                for (int j = 0; j < 8; ++j) pk[j] = (short)f2bf(v[j] * sc);
            }
            *(short8*)&Ad[LOFF(row, cs)] = pk;

            short8 pb;
            pb[0] = (short)rb[c][0].x; pb[1] = (short)rb[c][0].y;
            pb[2] = (short)rb[c][0].z; pb[3] = (short)rb[c][0].w;
            pb[4] = (short)rb[c][1].x; pb[5] = (short)rb[c][1].y;
            pb[6] = (short)rb[c][1].z; pb[7] = (short)rb[c][1].w;
            *(short8*)&Bd[LOFF(row, cs)] = pb;
        }
    };

    float4v acc[4][4];
#pragma unroll
    for (int i = 0; i < 4; ++i)
#pragma unroll
        for (int j = 0; j < 4; ++j)
#pragma unroll
            for (int r = 0; r < 4; ++r) acc[i][j][r] = 0.f;

    int nIt = Ktot >> 5;
    load_phase(0);
    store_phase(0, 0);

    for (int it = 0; it < nIt; ++it) {
        __syncthreads();
        int cur = it & 1;
        if (it + 1 < nIt) load_phase((it + 1) << 5);

        short8 af[4], bfr[4];
#pragma unroll
        for (int ms = 0; ms < 4; ++ms)
            af[ms] = *(const short8*)&As[cur * 4096 + ((wm * 4 + ms) * 4 + quad) * 128 + lane15 * 8];
#pragma unroll
        for (int ns = 0; ns < 4; ++ns)
            bfr[ns] = *(const short8*)&Bs[cur * 4096 + ((wn * 4 + ns) * 4 + quad) * 128 + lane15 * 8];
#pragma unroll
        for (int ms = 0; ms < 4; ++ms)
#pragma unroll
            for (int ns = 0; ns < 4; ++ns)
                acc[ms][ns] = __builtin_amdgcn_mfma_f32_16x16x32_bf16(
                    af[ms], bfr[ns], acc[ms][ns], 0, 0, 0);

        if (it + 1 < nIt) store_phase((it + 1) << 5, 1 - cur);
    }

    // ---- epilogue (identical math to round 3, which passed) ----
#pragma unroll
    for (int ms = 0; ms < 4; ++ms) {
#pragma unroll
        for (int r = 0; r < 4; ++r) {
            int m = m0 + wm * 64 + ms * 16 + quad * 4 + r;
#pragma unroll
            for (int ns = 0; ns < 4; ++ns) {
                int n = n0 + wn * 64 + ns * 16 + lane15;
                float vv = acc[ms][ns][r];
                if (MODE == 0) {
                    int b = m >> 11, t = m & (T_SEQ - 1);
                    int h = n >> 6,  d = n & 63;
                    Chead[(((b << 4) + h) * T_SEQ + t) * 64 + d] = f2bf(vv);
                } else {
                    vv += ldin(bias, n, fl);
                    if (fl) ((float*)outp)[m * 1024 + n] = vv;
                    else    ((u16*)outp)[m * 1024 + n] = f2bf(vv);
                }
            }
        }
    }
}

// ---------------------------------------------------------------------------
// 4) MFMA flash attention (unchanged from round 3 — passed, ~140 us)
// ---------------------------------------------------------------------------
__global__ __launch_bounds__(256) void attn_mfma(
    const u16* __restrict__ Qh, const u16* __restrict__ Kh,
    const u16* __restrict__ Vh, u16* __restrict__ AO)
{
    int bx = blockIdx.x;          // 1024 = B*H*(T/64)
    int qt = bx & 31;
    int bh = bx >> 5;             // 0..31
    int h  = bh & 15;
    int b  = bh >> 4;
    int tid = threadIdx.x;
    int l   = tid & 63;
    int w   = tid >> 6;
    int lane15 = l & 15;
    int quad   = l >> 4;

    __shared__ __align__(16) u16 Ks[64 * 72];
    __shared__ __align__(16) u16 Vt[64 * 72];   // transposed: [d][t_local]
    __shared__ __align__(16) u16 Ps[4 * 16 * 72];

    const u16* Qb = Qh + bh * (T_SEQ * 64);
    const u16* Kb = Kh + bh * (T_SEQ * 64);
    const u16* Vb = Vh + bh * (T_SEQ * 64);

    int qrow = qt * 64 + w * 16 + lane15;
    short8 qf[2];
#pragma unroll
    for (int ks = 0; ks < 2; ++ks)
        qf[ks] = *(const short8*)&Qb[qrow * 64 + ks * 32 + quad * 8];

    float4v oacc[4];
#pragma unroll
    for (int ds = 0; ds < 4; ++ds)
#pragma unroll
        for (int r = 0; r < 4; ++r) oacc[ds][r] = 0.f;
    float mrun[4], lrun[4];
#pragma unroll
    for (int r = 0; r < 4; ++r) { mrun[r] = -1e30f; lrun[r] = 0.f; }

    int srow = tid >> 2;
    int sdc  = (tid & 3) * 16;

    for (int kt = 0; kt <= qt; ++kt) {
        {
            const u16* kp = &Kb[(kt * 64 + srow) * 64 + sdc];
            ushort4 a = *(const ushort4*)kp;
            ushort4 c = *(const ushort4*)(kp + 4);
            ushort4 d2 = *(const ushort4*)(kp + 8);
            ushort4 e = *(const ushort4*)(kp + 12);
            short8 p0, p1;
            p0[0]=a.x; p0[1]=a.y; p0[2]=a.z; p0[3]=a.w;
            p0[4]=c.x; p0[5]=c.y; p0[6]=c.z; p0[7]=c.w;
            p1[0]=d2.x; p1[1]=d2.y; p1[2]=d2.z; p1[3]=d2.w;
            p1[4]=e.x; p1[5]=e.y; p1[6]=e.z; p1[7]=e.w;
            *(short8*)&Ks[srow * 72 + sdc] = p0;
            *(short8*)&Ks[srow * 72 + sdc + 8] = p1;

            const u16* vp = &Vb[(kt * 64 + srow) * 64 + sdc];
            u16 vv[16];
            *(ushort4*)&vv[0]  = *(const ushort4*)vp;
            *(ushort4*)&vv[4]  = *(const ushort4*)(vp + 4);
            *(ushort4*)&vv[8]  = *(const ushort4*)(vp + 8);
            *(ushort4*)&vv[12] = *(const ushort4*)(vp + 12);
#pragma unroll
            for (int e2 = 0; e2 < 16; ++e2)
                Vt[(sdc + e2) * 72 + srow] = vv[e2];
        }
        __syncthreads();

        float4v sacc[4];
#pragma unroll
        for (int ns = 0; ns < 4; ++ns)
#pragma unroll
            for (int r = 0; r < 4; ++r) sacc[ns][r] = 0.f;
#pragma unroll
        for (int ks = 0; ks < 2; ++ks) {
#pragma unroll
            for (int ns = 0; ns < 4; ++ns) {
                short8 bfk = *(const short8*)&Ks[(ns * 16 + lane15) * 72 + ks * 32 + quad * 8];
                sacc[ns] = __builtin_amdgcn_mfma_f32_16x16x32_bf16(
                    qf[ks], bfk, sacc[ns], 0, 0, 0);
            }
        }

        int qg0 = qt * 64 + w * 16 + quad * 4;
#pragma unroll
        for (int ns = 0; ns < 4; ++ns) {
            int kg = kt * 64 + ns * 16 + lane15;
#pragma unroll
            for (int r = 0; r < 4; ++r) {
                float s = sacc[ns][r] * 0.125f;
                sacc[ns][r] = (kg > qg0 + r) ? -1e30f : s;
            }
        }
#pragma unroll
        for (int r = 0; r < 4; ++r) {
            float mx = fmaxf(fmaxf(sacc[0][r], sacc[1][r]),
                             fmaxf(sacc[2][r], sacc[3][r]));
#pragma unroll
            for (int m2 = 1; m2 < 16; m2 <<= 1)
                mx = fmaxf(mx, __shfl_xor(mx, m2, 64));
            float mnew = fmaxf(mrun[r], mx);
            float al = __expf(mrun[r] - mnew);
            float rs = 0.f;
#pragma unroll
            for (int ns = 0; ns < 4; ++ns) {
                float p = __expf(sacc[ns][r] - mnew);
                sacc[ns][r] = p;
                rs += p;
            }
#pragma unroll
            for (int m2 = 1; m2 < 16; m2 <<= 1)
                rs += __shfl_xor(rs, m2, 64);
            lrun[r] = lrun[r] * al + rs;
            mrun[r] = mnew;
#pragma unroll
            for (int ds = 0; ds < 4; ++ds) oacc[ds][r] *= al;
        }

        u16* Pw = &Ps[w * 16 * 72];
#pragma unroll
        for (int ns = 0; ns < 4; ++ns)
#pragma unroll
            for (int r = 0; r < 4; ++r)
                Pw[(quad * 4 + r) * 72 + ns * 16 + lane15] = f2bf(sacc[ns][r]);

#pragma unroll
        for (int ks = 0; ks < 2; ++ks) {
            short8 afp = *(const short8*)&Pw[lane15 * 72 + ks * 32 + quad * 8];
#pragma unroll
            for (int ds = 0; ds < 4; ++ds) {
                short8 bfv = *(const short8*)&Vt[(ds * 16 + lane15) * 72 + ks * 32 + quad * 8];
                oacc[ds] = __builtin_amdgcn_mfma_f32_16x16x32_bf16(
                    afp, bfv, oacc[ds], 0, 0, 0);
            }
        }
        __syncthreads();
    }

#pragma unroll
    for (int r = 0; r < 4; ++r) {
        float inv = 1.f / lrun[r];
        int t = qt * 64 + w * 16 + quad * 4 + r;
        int orow = (b * T_SEQ + t) * 1024 + h * 64;
#pragma unroll
        for (int ds = 0; ds < 4; ++ds)
            AO[orow + ds * 16 + lane15] = f2bf(oacc[ds][r] * inv);
    }
}

// ---------------------------------------------------------------------------
extern "C" void kernel_launch(void* const* d_in, const int* in_sizes, int n_in,
                              void* d_out, int out_size, void* d_ws, size_t ws_size,
                              hipStream_t stream)
{
    const void* x   = d_in[0];
    const void* qWp = d_in[1];
    const void* qWi = d_in[2];
    const void* qWd = d_in[3];
    const void* qWg = d_in[4];
    const void* qbg = d_in[5];
    const void* kWp = d_in[6];
    const void* kWi = d_in[7];
    const void* kWd = d_in[8];
    const void* kWg = d_in[9];
    const void* kbg = d_in[10];
    const void* vWp = d_in[11];
    const void* vWi = d_in[12];
    const void* vWd = d_in[13];
    const void* vWg = d_in[14];
    const void* vbg = d_in[15];
    const void* oW  = d_in[16];
    const void* ob  = d_in[17];

    // ws layout (33 MiB total — unchanged, proven):
    int*   flag = (int*)d_ws;
    float* fws  = (float*)d_ws;
    float* csum = fws + 64;
    float* gq   = csum + 32768;
    float* gk   = gq + 3 * M_ROWS;
    float* gv   = gk + 3 * M_ROWS;
    const size_t SZ = (size_t)M_ROWS * D_MODEL;
    u16* Ib = (u16*)((char*)d_ws + (1u << 20));
    u16* AO = Ib;                  // alias, disjoint in time
    u16* Qh = Ib + SZ;
    u16* Kh = Qh + SZ;
    u16* Vh = Kh + SZ;

    detect_kernel<<<1, 64, 0, stream>>>((const u32*)x, flag);
    scan_partial<<<128, 256, 0, stream>>>(x, csum, flag);
    scan_final<<<128, 256, 0, stream>>>(x, csum, Ib, flag);
    gates_kernel<<<M_ROWS, 64, 0, stream>>>(x, qWg, qbg, kWg, kbg, vWg, vbg,
                                            gq, gk, gv, flag);

    GemmArgs pa;
    pa.W[0][0] = qWp; pa.W[0][1] = qWi; pa.W[0][2] = qWd;
    pa.W[1][0] = kWp; pa.W[1][1] = kWi; pa.W[1][2] = kWd;
    pa.W[2][0] = vWp; pa.W[2][1] = vWi; pa.W[2][2] = vWd;
    pa.G[0] = gq; pa.G[1] = gk; pa.G[2] = gv;
    pa.C[0] = Qh; pa.C[1] = Kh; pa.C[2] = Vh;
    mfma_gemm<0><<<dim3(8, 32, 3), 256, 0, stream>>>(
        x, Ib, nullptr, pa, nullptr, nullptr, flag, 3072);

    attn_mfma<<<B_SZ * N_HEADS * (T_SEQ / 64), 256, 0, stream>>>(Qh, Kh, Vh, AO);

    GemmArgs oa = {};
    oa.W[0][0] = oW;
    mfma_gemm<1><<<dim3(8, 32, 1), 256, 0, stream>>>(
        nullptr, nullptr, AO, oa, ob, d_out, flag, 1024);
}